// Round 3
// baseline (5178.742 us; speedup 1.0000x reference)
//
#include <hip/hip_runtime.h>

// Sizes (fixed by the problem)
#define TT 256
#define BB 32
#define EE 512
#define HH 256
#define GG 1024   // 4*H
#define NK 17

typedef _Float16 h2_t __attribute__((ext_vector_type(2)));

__device__ __forceinline__ unsigned short f2h_bits(float f) {
  _Float16 h = (_Float16)f;
  return __builtin_bit_cast(unsigned short, h);
}
__device__ __forceinline__ float dot2(unsigned int w, unsigned int h, float acc) {
#if __has_builtin(__builtin_amdgcn_fdot2)
  return __builtin_amdgcn_fdot2(__builtin_bit_cast(h2_t, w), __builtin_bit_cast(h2_t, h), acc, false);
#else
  h2_t wv = __builtin_bit_cast(h2_t, w), hv = __builtin_bit_cast(h2_t, h);
  acc = fmaf((float)wv.x, (float)hv.x, acc);
  return fmaf((float)wv.y, (float)hv.y, acc);
#endif
}

// ---------------------------------------------------------------- embedding
__global__ void k_embed(const int* __restrict__ src,
                        const float* __restrict__ emb,
                        float* __restrict__ xin) {
  int row = blockIdx.x;                 // b*T + t, 8192 rows
  int v = src[row];                     // emb[0] is all-zero, so padding is fine
  const float4* e = reinterpret_cast<const float4*>(emb + (size_t)v * EE);
  float4* o = reinterpret_cast<float4*>(xin + (size_t)row * EE);
  o[threadIdx.x] = e[threadIdx.x];      // 128 threads * 16B
}

// ---------------------------------------------- Whh -> packed f16 [ld][kk][g]
// wpk[ld][kk][g] = pack(f16(W[ld][g][2kk]), f16(W[ld][g][2kk+1]))
__global__ void k_prep_wpk(const float* __restrict__ whh,
                           unsigned int* __restrict__ wpk) {
  int idx = blockIdx.x * 256 + threadIdx.x;   // < 4*128*1024 = 524288
  int g = idx & 1023;
  int kk = (idx >> 10) & 127;
  int ld = idx >> 17;
  const float* row = whh + ((size_t)ld * GG + g) * HH + 2 * kk;
  unsigned int lo = f2h_bits(row[0]);
  unsigned int hi = f2h_bits(row[1]);
  wpk[idx] = lo | (hi << 16);
}

__global__ void k_prep_bias(const float* __restrict__ bih,
                            const float* __restrict__ bhh,
                            float* __restrict__ bias) {
  int i = blockIdx.x * 256 + threadIdx.x;     // < 4096
  bias[i] = bih[i] + bhh[i];
}

// ------------------------------------------------------------- xg GEMM
// out[m][g] = sum_k X[m][k]*W[g][k] + bias[g];  M=8192, N=1024, K=512
__global__ __launch_bounds__(256) void k_gemm(
    const float* __restrict__ X,    // [8192][512] f32
    const float* __restrict__ W,    // [1024][512] f32 (row g)
    const float* __restrict__ bias, // [1024]
    float* __restrict__ out) {      // [8192][1024] f32
  __shared__ float Xs[32][68];   // [k][m], padded
  __shared__ float Ws[32][68];   // [k][n]
  const int tid = threadIdx.x;
  const int tx = tid & 15, ty = tid >> 4;
  const int m0 = blockIdx.y * 64, n0 = blockIdx.x * 64;
  const int lr = tid >> 2;          // 0..63
  const int lc = (tid & 3) * 8;     // 0,8,16,24
  float acc[4][4] = {};
  for (int k0 = 0; k0 < EE; k0 += 32) {
    float4 xa = *reinterpret_cast<const float4*>(X + (size_t)(m0 + lr) * EE + k0 + lc);
    float4 xb = *reinterpret_cast<const float4*>(X + (size_t)(m0 + lr) * EE + k0 + lc + 4);
    float4 wa = *reinterpret_cast<const float4*>(W + (size_t)(n0 + lr) * EE + k0 + lc);
    float4 wb = *reinterpret_cast<const float4*>(W + (size_t)(n0 + lr) * EE + k0 + lc + 4);
    Xs[lc + 0][lr] = xa.x; Xs[lc + 1][lr] = xa.y; Xs[lc + 2][lr] = xa.z; Xs[lc + 3][lr] = xa.w;
    Xs[lc + 4][lr] = xb.x; Xs[lc + 5][lr] = xb.y; Xs[lc + 6][lr] = xb.z; Xs[lc + 7][lr] = xb.w;
    Ws[lc + 0][lr] = wa.x; Ws[lc + 1][lr] = wa.y; Ws[lc + 2][lr] = wa.z; Ws[lc + 3][lr] = wa.w;
    Ws[lc + 4][lr] = wb.x; Ws[lc + 5][lr] = wb.y; Ws[lc + 6][lr] = wb.z; Ws[lc + 7][lr] = wb.w;
    __syncthreads();
#pragma unroll
    for (int k = 0; k < 32; ++k) {
      float4 a = *reinterpret_cast<const float4*>(&Xs[k][ty * 4]);
      float4 b = *reinterpret_cast<const float4*>(&Ws[k][tx * 4]);
      float av[4] = {a.x, a.y, a.z, a.w};
      float bv[4] = {b.x, b.y, b.z, b.w};
#pragma unroll
      for (int i = 0; i < 4; ++i)
#pragma unroll
        for (int j = 0; j < 4; ++j) acc[i][j] = fmaf(av[i], bv[j], acc[i][j]);
    }
    __syncthreads();
  }
  const int n = n0 + tx * 4;
#pragma unroll
  for (int i = 0; i < 4; ++i) {
    float4 o;
    o.x = acc[i][0] + bias[n + 0];
    o.y = acc[i][1] + bias[n + 1];
    o.z = acc[i][2] + bias[n + 2];
    o.w = acc[i][3] + bias[n + 3];
    *reinterpret_cast<float4*>(out + (size_t)(m0 + ty * 4 + i) * GG + n) = o;
  }
}

// ------------------------------------------------------------- LSTM recurrence
// 128 blocks x 512 threads. Block pair (2p, 2p+1) handles (b,dir)=p; each block
// owns all 4 gates for 128 h-columns, weights register-resident (f16 packed).
// Per-step 256B h-chunk exchange via global pub buffer + release/acquire flags.
__global__ __launch_bounds__(512, 2) void k_rec(
    const float* __restrict__ xg,        // [2][8192][1024] dir-major, bias included
    const unsigned int* __restrict__ wpk,// this layer: [2][128][1024] packed f16
    const int* __restrict__ lens,        // [32]
    float* __restrict__ outx,            // [8192][512]: [:256]=fwd, [256:]=bwd
    unsigned int* __restrict__ pub,      // [64][2][2][64]
    unsigned int* __restrict__ flags) {  // this layer: [64][2], pre-zeroed
  const int bid = blockIdx.x;            // 0..127
  const int pair = bid >> 1;             // 0..63
  const int chunk = bid & 1;
  const int b = pair & 31;
  const int dir = pair >> 5;
  const int tid = threadIdx.x;           // 0..511
  const int gate = tid >> 7;             // 0..3 = i,f,g,o
  const int jj = tid & 127;
  const int g_orig = gate * 256 + chunk * 128 + jj;
  __shared__ __align__(16) unsigned short hb16[256];  // h (f16), full 256
  __shared__ float pre[512];

  // weight preload: 128 VGPRs per lane (w[kk] = W[g_orig][2kk..2kk+1])
  const unsigned int* wp = wpk + (size_t)dir * (128 * 1024) + g_orig;
  unsigned int w[128];
#pragma unroll
  for (int kk = 0; kk < 128; ++kk) w[kk] = wp[(size_t)kk * 1024];

  if (tid < 128) reinterpret_cast<unsigned int*>(hb16)[tid] = 0;
  __syncthreads();

  const int len = lens[b];
  const float* xgb = xg + ((size_t)dir * (BB * TT) + (size_t)b * TT) * GG + g_orig;
  float c = 0.f;
  const int wv = tid >> 6;               // wave id 0..7
  unsigned int* mypub = pub + (size_t)((pair * 2 + chunk) * 2) * 64;
  const unsigned int* papub = pub + (size_t)((pair * 2 + (chunk ^ 1)) * 2) * 64;
  unsigned int* myflag = flags + pair * 2 + chunk;
  const unsigned int* pflag = flags + pair * 2 + (chunk ^ 1);

  for (int s = 0; s < TT; ++s) {
    const int t = dir ? (TT - 1 - s) : s;
    float acc = xgb[(size_t)t * GG];
    const uint4* h4 = reinterpret_cast<const uint4*>(hb16);
#pragma unroll
    for (int q = 0; q < 32; ++q) {
      uint4 hv = h4[q];
      acc = dot2(w[4 * q + 0], hv.x, acc);
      acc = dot2(w[4 * q + 1], hv.y, acc);
      acc = dot2(w[4 * q + 2], hv.z, acc);
      acc = dot2(w[4 * q + 3], hv.w, acc);
    }
    pre[tid] = acc;
    __syncthreads();                     // bar1: dot done, pre[] complete
    const bool last = (s == TT - 1);
    if (tid < 128) {                     // waves 0,1: elementwise for own 128 h-cols
      float gi = pre[tid], gf = pre[128 + tid], g2 = pre[256 + tid], go = pre[384 + tid];
      float iv = 1.f / (1.f + expf(-gi));
      float fv = 1.f / (1.f + expf(-gf));
      float gv = tanhf(g2);
      float ov = 1.f / (1.f + expf(-go));
      float cn = fv * c + iv * gv;
      float hn = ov * tanhf(cn);
      const bool m = (t < len);
      outx[((size_t)(b * TT) + t) * (2 * HH) + dir * HH + chunk * 128 + tid] = m ? hn : 0.f;
      if (m) {
        c = cn;
        hb16[chunk * 128 + tid] = f2h_bits(hn);
      }
    }
    __syncthreads();                     // bar2: hb16 own-half current
    if (!last) {
      if (wv == 0) {                     // publish own half (64 dwords)
        mypub[(s & 1) * 64 + tid] = reinterpret_cast<const unsigned int*>(hb16)[chunk * 64 + tid];
        __threadfence();
        if (tid == 0)
          __hip_atomic_store(myflag, (unsigned int)(s + 1), __ATOMIC_RELEASE, __HIP_MEMORY_SCOPE_AGENT);
      } else if (wv == 2) {              // fetch partner half
        const int ll = tid - 128;
        while (__hip_atomic_load(pflag, __ATOMIC_ACQUIRE, __HIP_MEMORY_SCOPE_AGENT) < (unsigned int)(s + 1))
          __builtin_amdgcn_s_sleep(1);
        reinterpret_cast<unsigned int*>(hb16)[(chunk ^ 1) * 64 + ll] = papub[(s & 1) * 64 + ll];
      }
    }
    __syncthreads();                     // bar3: hb16 fully h^{s+1}
  }
}

// ------------------------------------------------------------- logits
__global__ __launch_bounds__(256) void k_logits(
    const float* __restrict__ feats,  // [8192][512] f32
    const float* __restrict__ wlin,   // [17][512] f32
    const float* __restrict__ blin,   // [17]
    float* __restrict__ logits) {     // [8192][17]
  int o = blockIdx.x * 256 + threadIdx.x;      // < 8192*17 = 139264 exactly
  int m = o / NK, jj = o - m * NK;
  const float4* fr = reinterpret_cast<const float4*>(feats + (size_t)m * EE);
  const float4* wr = reinterpret_cast<const float4*>(wlin + (size_t)jj * EE);
  float s = blin[jj];
  for (int q = 0; q < EE / 4; ++q) {
    float4 fv = fr[q], wv = wr[q];
    s = fmaf(fv.x, wv.x, s);
    s = fmaf(fv.y, wv.y, s);
    s = fmaf(fv.z, wv.z, s);
    s = fmaf(fv.w, wv.w, s);
  }
  logits[o] = s;
}

// ------------------------------------------------------------- CRF NLL per batch
__global__ __launch_bounds__(64) void k_crf(
    const float* __restrict__ logits,   // [32][256][17]
    const int* __restrict__ labels,     // [32][256]
    const int* __restrict__ lens,       // [32]
    const float* __restrict__ trans,    // [17][17]
    const float* __restrict__ startv,   // [17]
    const float* __restrict__ endv,     // [17]
    float* __restrict__ res) {          // [32] = numerator - partition
  const int b = blockIdx.x;
  const int tid = threadIdx.x;          // one wave
  __shared__ float trs[NK * NK];
  __shared__ float alpha[NK];
  for (int i = tid; i < NK * NK; i += 64) trs[i] = trans[i];
  const int len = lens[b];
  const int* lab = labels + b * TT;
  const float* lg = logits + (size_t)b * TT * NK;
  float part = 0.f;
  for (int t = tid; t < TT; t += 64)
    if (t < len) part += lg[t * NK + lab[t]];
  __syncthreads();
  for (int t = tid; t < TT - 1; t += 64)
    if (t + 1 < len) part += trs[lab[t] * NK + lab[t + 1]];
#pragma unroll
  for (int off = 32; off > 0; off >>= 1) part += __shfl_down(part, off);
  if (tid < NK) alpha[tid] = startv[tid] + lg[tid];
  __syncthreads();
  const int tmax = (len < TT) ? len : TT;
  for (int t = 1; t < tmax; ++t) {
    float nv = 0.f;
    if (tid < NK) {
      float mx = -1e30f;
#pragma unroll
      for (int i = 0; i < NK; ++i) mx = fmaxf(mx, alpha[i] + trs[i * NK + tid]);
      float sum = 0.f;
#pragma unroll
      for (int i = 0; i < NK; ++i) sum += expf(alpha[i] + trs[i * NK + tid] - mx);
      nv = mx + logf(sum) + lg[t * NK + tid];
    }
    __syncthreads();
    if (tid < NK) alpha[tid] = nv;
    __syncthreads();
  }
  if (tid == 0) {
    float mx = -1e30f;
    float av[NK];
    for (int i = 0; i < NK; ++i) { av[i] = alpha[i] + endv[i]; mx = fmaxf(mx, av[i]); }
    float sum = 0.f;
    for (int i = 0; i < NK; ++i) sum += expf(av[i] - mx);
    float partition = mx + logf(sum);
    float numer = startv[lab[0]] + part + endv[lab[len - 1]];
    res[b] = numer - partition;
  }
}

__global__ void k_final(const float* __restrict__ res, float* __restrict__ out) {
  int tid = threadIdx.x;  // 64
  float v = (tid < BB) ? res[tid] : 0.f;
#pragma unroll
  for (int off = 32; off > 0; off >>= 1) v += __shfl_down(v, off);
  if (tid == 0) out[0] = -v;
}

extern "C" void kernel_launch(void* const* d_in, const int* in_sizes, int n_in,
                              void* d_out, int out_size, void* d_ws, size_t ws_size,
                              hipStream_t stream) {
  const int* src = (const int*)d_in[0];
  const int* lens = (const int*)d_in[1];
  const int* labels = (const int*)d_in[2];
  // d_in[3] = decode (always 0, ignored)
  const float* emb = (const float*)d_in[4];
  const float* Wih = (const float*)d_in[5];
  const float* Whh = (const float*)d_in[6];
  const float* bih = (const float*)d_in[7];
  const float* bhh = (const float*)d_in[8];
  const float* Wlin = (const float*)d_in[9];
  const float* blin = (const float*)d_in[10];
  const float* trans = (const float*)d_in[11];
  const float* startv = (const float*)d_in[12];
  const float* endv = (const float*)d_in[13];

  char* w = (char*)d_ws;
  float* xin0 = (float*)w;  w += (size_t)BB * TT * EE * 4;        // 16.8 MB
  float* xin1 = (float*)w;  w += (size_t)BB * TT * EE * 4;        // 16.8 MB
  float* xg = (float*)w;    w += (size_t)2 * BB * TT * GG * 4;    // 67.1 MB
  unsigned int* wpk = (unsigned int*)w; w += (size_t)4 * 128 * 1024 * 4;  // 2.1 MB
  float* biasb = (float*)w; w += (size_t)2 * 2 * GG * 4;          // 16 KB
  float* logits = (float*)w; w += (size_t)BB * TT * NK * 4;       // 557 KB
  float* res = (float*)w;   w += 256;
  unsigned int* pub = (unsigned int*)w;   w += (size_t)64 * 2 * 2 * 64 * 4;  // 128 KB
  unsigned int* flags = (unsigned int*)w; w += (size_t)2 * 64 * 2 * 4;       // 1 KB

  hipMemsetAsync(flags, 0, 2 * 64 * 2 * sizeof(unsigned int), stream);
  k_embed<<<BB * TT, 128, 0, stream>>>(src, emb, xin0);
  k_prep_wpk<<<(4 * 128 * 1024) / 256, 256, 0, stream>>>(Whh, wpk);
  k_prep_bias<<<16, 256, 0, stream>>>(bih, bhh, biasb);

  for (int l = 0; l < 2; ++l) {
    const float* xin = l ? xin1 : xin0;
    float* xout = l ? xin0 : xin1;
    for (int d = 0; d < 2; ++d) {
      k_gemm<<<dim3(GG / 64, (BB * TT) / 64), 256, 0, stream>>>(
          xin, Wih + ((size_t)(l * 2 + d)) * GG * EE,
          biasb + (l * 2 + d) * GG, xg + (size_t)d * BB * TT * GG);
    }
    k_rec<<<128, 512, 0, stream>>>(xg, wpk + (size_t)l * 2 * 128 * 1024, lens, xout,
                                   pub, flags + l * 128);
  }

  k_logits<<<(BB * TT * NK) / 256, 256, 0, stream>>>(xin0, Wlin, blin, logits);
  k_crf<<<BB, 64, 0, stream>>>(logits, labels, lens, trans, startv, endv, res);
  k_final<<<1, 64, 0, stream>>>(res, (float*)d_out);
}

// Round 4
// 1468.918 us; speedup vs baseline: 3.5255x; 3.5255x over previous
//
#include <hip/hip_runtime.h>

// Sizes (fixed by the problem)
#define TT 256
#define BB 32
#define EE 512
#define HH 256
#define GG 1024   // 4*H
#define NK 17

__device__ __forceinline__ int dot4i8(int a, int b, int c) {
#if __has_builtin(__builtin_amdgcn_sdot4)
  return __builtin_amdgcn_sdot4(a, b, c, false);
#else
  int r = c;
#pragma unroll
  for (int e = 0; e < 4; ++e) {
    int av = (a << (24 - 8 * e)) >> 24;
    int bv = (b << (24 - 8 * e)) >> 24;
    r += av * bv;
  }
  return r;
#endif
}

// ---------------------------------------------------------------- embedding
__global__ void k_embed(const int* __restrict__ src,
                        const float* __restrict__ emb,
                        float* __restrict__ xin) {
  int row = blockIdx.x;                 // b*T + t, 8192 rows
  int v = src[row];                     // emb[0] is all-zero, so padding is fine
  const float4* e = reinterpret_cast<const float4*>(emb + (size_t)v * EE);
  float4* o = reinterpret_cast<float4*>(xin + (size_t)row * EE);
  o[threadIdx.x] = e[threadIdx.x];      // 128 threads * 16B
}

// ------------------------------------------------- per-(l,d) max|Whh| (abs bits)
__global__ void k_maxabs(const float* __restrict__ whh, unsigned int* __restrict__ mx) {
  int idx = blockIdx.x * 256 + threadIdx.x;   // < 4*1024*256 = 1048576
  int ld = idx >> 18;                         // block (and wave) spans a single ld
  float v = fabsf(whh[idx]);
#pragma unroll
  for (int off = 32; off > 0; off >>= 1) v = fmaxf(v, __shfl_down(v, off));
  if ((threadIdx.x & 63) == 0) atomicMax(mx + ld, __float_as_uint(v));
}

// ---------------------------------------- Whh -> int8, layout [ld][kk=64][g=1024]
// wq[ld][kk][g] packs W[ld][g][4kk..4kk+3] / s * 127, rounded.
__global__ void k_quant(const float* __restrict__ whh,
                        const unsigned int* __restrict__ mx,
                        int* __restrict__ wq) {
  int idx = blockIdx.x * 256 + threadIdx.x;   // < 4*64*1024 = 262144
  int g = idx & 1023;
  int kk = (idx >> 10) & 63;
  int ld = idx >> 16;
  float inv = 127.f / __uint_as_float(mx[ld]);
  const float* row = whh + ((size_t)(ld * GG + g)) * HH + 4 * kk;
  int q0 = (int)rintf(row[0] * inv);
  int q1 = (int)rintf(row[1] * inv);
  int q2 = (int)rintf(row[2] * inv);
  int q3 = (int)rintf(row[3] * inv);
  wq[idx] = (q0 & 0xFF) | ((q1 & 0xFF) << 8) | ((q2 & 0xFF) << 16) | ((q3 & 0xFF) << 24);
}

__global__ void k_prep_bias(const float* __restrict__ bih,
                            const float* __restrict__ bhh,
                            float* __restrict__ bias) {
  int i = blockIdx.x * 256 + threadIdx.x;     // < 4096
  bias[i] = bih[i] + bhh[i];
}

// ------------------------------------------------------------- xg GEMM
// out[m][g] = sum_k X[m][k]*W[g][k] + bias[g];  M=8192, N=1024, K=512
__global__ __launch_bounds__(256) void k_gemm(
    const float* __restrict__ X,    // [8192][512] f32
    const float* __restrict__ W,    // [1024][512] f32 (row g)
    const float* __restrict__ bias, // [1024]
    float* __restrict__ out) {      // [8192][1024] f32
  __shared__ float Xs[32][68];   // [k][m], padded
  __shared__ float Ws[32][68];   // [k][n]
  const int tid = threadIdx.x;
  const int tx = tid & 15, ty = tid >> 4;
  const int m0 = blockIdx.y * 64, n0 = blockIdx.x * 64;
  const int lr = tid >> 2;          // 0..63
  const int lc = (tid & 3) * 8;     // 0,8,16,24
  float acc[4][4] = {};
  for (int k0 = 0; k0 < EE; k0 += 32) {
    float4 xa = *reinterpret_cast<const float4*>(X + (size_t)(m0 + lr) * EE + k0 + lc);
    float4 xb = *reinterpret_cast<const float4*>(X + (size_t)(m0 + lr) * EE + k0 + lc + 4);
    float4 wa = *reinterpret_cast<const float4*>(W + (size_t)(n0 + lr) * EE + k0 + lc);
    float4 wb = *reinterpret_cast<const float4*>(W + (size_t)(n0 + lr) * EE + k0 + lc + 4);
    Xs[lc + 0][lr] = xa.x; Xs[lc + 1][lr] = xa.y; Xs[lc + 2][lr] = xa.z; Xs[lc + 3][lr] = xa.w;
    Xs[lc + 4][lr] = xb.x; Xs[lc + 5][lr] = xb.y; Xs[lc + 6][lr] = xb.z; Xs[lc + 7][lr] = xb.w;
    Ws[lc + 0][lr] = wa.x; Ws[lc + 1][lr] = wa.y; Ws[lc + 2][lr] = wa.z; Ws[lc + 3][lr] = wa.w;
    Ws[lc + 4][lr] = wb.x; Ws[lc + 5][lr] = wb.y; Ws[lc + 6][lr] = wb.z; Ws[lc + 7][lr] = wb.w;
    __syncthreads();
#pragma unroll
    for (int k = 0; k < 32; ++k) {
      float4 a = *reinterpret_cast<const float4*>(&Xs[k][ty * 4]);
      float4 b = *reinterpret_cast<const float4*>(&Ws[k][tx * 4]);
      float av[4] = {a.x, a.y, a.z, a.w};
      float bv[4] = {b.x, b.y, b.z, b.w};
#pragma unroll
      for (int i = 0; i < 4; ++i)
#pragma unroll
        for (int j = 0; j < 4; ++j) acc[i][j] = fmaf(av[i], bv[j], acc[i][j]);
    }
    __syncthreads();
  }
  const int n = n0 + tx * 4;
#pragma unroll
  for (int i = 0; i < 4; ++i) {
    float4 o;
    o.x = acc[i][0] + bias[n + 0];
    o.y = acc[i][1] + bias[n + 1];
    o.z = acc[i][2] + bias[n + 2];
    o.w = acc[i][3] + bias[n + 3];
    *reinterpret_cast<float4*>(out + (size_t)(m0 + ty * 4 + i) * GG + n) = o;
  }
}

// ------------------------------------------------------------- LSTM recurrence
// One block per (b,dir); 512 threads; weights int8 register-resident
// (128 VGPRs/lane). h quantized to int8 in LDS (64 broadcast dwords).
// No cross-block communication; 2 intra-CU barriers per step.
__global__ __launch_bounds__(512, 1) void k_rec(
    const float* __restrict__ xg,        // [2][8192][1024] dir-major, bias included
    const int* __restrict__ wq,          // this layer: [2][64][1024] packed int8
    const unsigned int* __restrict__ mx, // this layer: [2] abs-max bits
    const int* __restrict__ lens,        // [32]
    float* __restrict__ outx)            // [8192][512]: [:256]=fwd, [256:]=bwd
{
  const int bid = blockIdx.x;            // 0..63
  const int b = bid & 31;
  const int dir = bid >> 5;
  const int L = threadIdx.x;             // 0..511
  const int g0 = L, g1 = L + 512;        // covers i,f | g,o gate columns
  __shared__ float pre[GG];
  __shared__ __align__(16) int hq[64];   // 256 int8 h values
  const float f = __uint_as_float(mx[dir]) / (127.f * 127.f);
  const int* wp = wq + (size_t)dir * 64 * 1024;
  int w0[64], w1[64];
#pragma unroll
  for (int kk = 0; kk < 64; ++kk) {
    w0[kk] = wp[kk * 1024 + g0];
    w1[kk] = wp[kk * 1024 + g1];
  }
  if (L < 64) hq[L] = 0;
  float c = 0.f;
  const int len = lens[b];
  const float* xgb = xg + ((size_t)dir * (BB * TT) + (size_t)b * TT) * GG;
  __syncthreads();
  for (int s = 0; s < TT; ++s) {
    const int t = dir ? (TT - 1 - s) : s;
    // xg loads issued early; consumed only after the int dot (latency hidden)
    float xv0 = xgb[(size_t)t * GG + g0];
    float xv1 = xgb[(size_t)t * GG + g1];
    int a0 = 0, a1 = 0;
    const uint4* h4 = reinterpret_cast<const uint4*>(hq);
#pragma unroll
    for (int q = 0; q < 16; ++q) {
      uint4 hv = h4[q];
      a0 = dot4i8(w0[4 * q + 0], (int)hv.x, a0);
      a0 = dot4i8(w0[4 * q + 1], (int)hv.y, a0);
      a0 = dot4i8(w0[4 * q + 2], (int)hv.z, a0);
      a0 = dot4i8(w0[4 * q + 3], (int)hv.w, a0);
      a1 = dot4i8(w1[4 * q + 0], (int)hv.x, a1);
      a1 = dot4i8(w1[4 * q + 1], (int)hv.y, a1);
      a1 = dot4i8(w1[4 * q + 2], (int)hv.z, a1);
      a1 = dot4i8(w1[4 * q + 3], (int)hv.w, a1);
    }
    pre[g0] = xv0 + (float)a0 * f;
    pre[g1] = xv1 + (float)a1 * f;
    __syncthreads();                     // bar1: pre[] complete (hq reads done too)
    if (L < HH) {
      float gi = pre[L], gf = pre[HH + L], g2 = pre[2 * HH + L], go = pre[3 * HH + L];
      float iv = 1.f / (1.f + expf(-gi));
      float fv = 1.f / (1.f + expf(-gf));
      float gv = tanhf(g2);
      float ov = 1.f / (1.f + expf(-go));
      float cn = fv * c + iv * gv;
      float hn = ov * tanhf(cn);
      const bool m = (t < len);
      outx[((size_t)(b * TT) + t) * (2 * HH) + dir * HH + L] = m ? hn : 0.f;
      if (m) {
        c = cn;
        reinterpret_cast<char*>(hq)[L] = (char)(int)rintf(hn * 127.f);
      }
    }
    __syncthreads();                     // bar2: hq holds h^{s+1}
  }
}

// ------------------------------------------------------------- logits
__global__ __launch_bounds__(256) void k_logits(
    const float* __restrict__ feats,  // [8192][512] f32
    const float* __restrict__ wlin,   // [17][512] f32
    const float* __restrict__ blin,   // [17]
    float* __restrict__ logits) {     // [8192][17]
  int o = blockIdx.x * 256 + threadIdx.x;      // < 8192*17 = 139264 exactly
  int m = o / NK, jj = o - m * NK;
  const float4* fr = reinterpret_cast<const float4*>(feats + (size_t)m * EE);
  const float4* wr = reinterpret_cast<const float4*>(wlin + (size_t)jj * EE);
  float s = blin[jj];
  for (int q = 0; q < EE / 4; ++q) {
    float4 fv = fr[q], wv = wr[q];
    s = fmaf(fv.x, wv.x, s);
    s = fmaf(fv.y, wv.y, s);
    s = fmaf(fv.z, wv.z, s);
    s = fmaf(fv.w, wv.w, s);
  }
  logits[o] = s;
}

// ------------------------------------------------------------- CRF NLL per batch
__global__ __launch_bounds__(64) void k_crf(
    const float* __restrict__ logits,   // [32][256][17]
    const int* __restrict__ labels,     // [32][256]
    const int* __restrict__ lens,       // [32]
    const float* __restrict__ trans,    // [17][17]
    const float* __restrict__ startv,   // [17]
    const float* __restrict__ endv,     // [17]
    float* __restrict__ res) {          // [32] = numerator - partition
  const int b = blockIdx.x;
  const int tid = threadIdx.x;          // one wave
  __shared__ float trs[NK * NK];
  __shared__ float alpha[NK];
  for (int i = tid; i < NK * NK; i += 64) trs[i] = trans[i];
  const int len = lens[b];
  const int* lab = labels + b * TT;
  const float* lg = logits + (size_t)b * TT * NK;
  float part = 0.f;
  for (int t = tid; t < TT; t += 64)
    if (t < len) part += lg[t * NK + lab[t]];
  __syncthreads();
  for (int t = tid; t < TT - 1; t += 64)
    if (t + 1 < len) part += trs[lab[t] * NK + lab[t + 1]];
#pragma unroll
  for (int off = 32; off > 0; off >>= 1) part += __shfl_down(part, off);
  if (tid < NK) alpha[tid] = startv[tid] + lg[tid];
  __syncthreads();
  const int tmax = (len < TT) ? len : TT;
  for (int t = 1; t < tmax; ++t) {
    float nv = 0.f;
    if (tid < NK) {
      float mxv = -1e30f;
#pragma unroll
      for (int i = 0; i < NK; ++i) mxv = fmaxf(mxv, alpha[i] + trs[i * NK + tid]);
      float sum = 0.f;
#pragma unroll
      for (int i = 0; i < NK; ++i) sum += expf(alpha[i] + trs[i * NK + tid] - mxv);
      nv = mxv + logf(sum) + lg[t * NK + tid];
    }
    __syncthreads();
    if (tid < NK) alpha[tid] = nv;
    __syncthreads();
  }
  if (tid == 0) {
    float mxv = -1e30f;
    float av[NK];
    for (int i = 0; i < NK; ++i) { av[i] = alpha[i] + endv[i]; mxv = fmaxf(mxv, av[i]); }
    float sum = 0.f;
    for (int i = 0; i < NK; ++i) sum += expf(av[i] - mxv);
    float partition = mxv + logf(sum);
    float numer = startv[lab[0]] + part + endv[lab[len - 1]];
    res[b] = numer - partition;
  }
}

__global__ void k_final(const float* __restrict__ res, float* __restrict__ out) {
  int tid = threadIdx.x;  // 64
  float v = (tid < BB) ? res[tid] : 0.f;
#pragma unroll
  for (int off = 32; off > 0; off >>= 1) v += __shfl_down(v, off);
  if (tid == 0) out[0] = -v;
}

extern "C" void kernel_launch(void* const* d_in, const int* in_sizes, int n_in,
                              void* d_out, int out_size, void* d_ws, size_t ws_size,
                              hipStream_t stream) {
  const int* src = (const int*)d_in[0];
  const int* lens = (const int*)d_in[1];
  const int* labels = (const int*)d_in[2];
  // d_in[3] = decode (always 0, ignored)
  const float* emb = (const float*)d_in[4];
  const float* Wih = (const float*)d_in[5];
  const float* Whh = (const float*)d_in[6];
  const float* bih = (const float*)d_in[7];
  const float* bhh = (const float*)d_in[8];
  const float* Wlin = (const float*)d_in[9];
  const float* blin = (const float*)d_in[10];
  const float* trans = (const float*)d_in[11];
  const float* startv = (const float*)d_in[12];
  const float* endv = (const float*)d_in[13];

  char* w = (char*)d_ws;
  float* xin0 = (float*)w;  w += (size_t)BB * TT * EE * 4;        // 16.8 MB
  float* xin1 = (float*)w;  w += (size_t)BB * TT * EE * 4;        // 16.8 MB
  float* xg = (float*)w;    w += (size_t)2 * BB * TT * GG * 4;    // 67.1 MB
  int* wq = (int*)w;        w += (size_t)4 * 64 * 1024 * 4;       // 1.05 MB
  unsigned int* mxb = (unsigned int*)w; w += 256;                 // 4 maxabs
  float* biasb = (float*)w; w += (size_t)2 * 2 * GG * 4;          // 16 KB
  float* logits = (float*)w; w += (size_t)BB * TT * NK * 4;       // 557 KB
  float* res = (float*)w;   w += 256;

  hipMemsetAsync(mxb, 0, 16, stream);
  k_embed<<<BB * TT, 128, 0, stream>>>(src, emb, xin0);
  k_maxabs<<<4096, 256, 0, stream>>>(Whh, mxb);
  k_quant<<<1024, 256, 0, stream>>>(Whh, mxb, wq);
  k_prep_bias<<<16, 256, 0, stream>>>(bih, bhh, biasb);

  for (int l = 0; l < 2; ++l) {
    const float* xin = l ? xin1 : xin0;
    float* xout = l ? xin0 : xin1;
    for (int d = 0; d < 2; ++d) {
      k_gemm<<<dim3(GG / 64, (BB * TT) / 64), 256, 0, stream>>>(
          xin, Wih + ((size_t)(l * 2 + d)) * GG * EE,
          biasb + (l * 2 + d) * GG, xg + (size_t)d * BB * TT * GG);
    }
    k_rec<<<64, 512, 0, stream>>>(xg, wq + (size_t)l * 2 * 64 * 1024, mxb + l * 2,
                                  lens, xout);
  }

  k_logits<<<(BB * TT * NK) / 256, 256, 0, stream>>>(xin0, Wlin, blin, logits);
  k_crf<<<BB, 64, 0, stream>>>(logits, labels, lens, trans, startv, endv, res);
  k_final<<<1, 64, 0, stream>>>(res, (float*)d_out);
}

// Round 5
// 1132.099 us; speedup vs baseline: 4.5745x; 1.2975x over previous
//
#include <hip/hip_runtime.h>

// Sizes (fixed by the problem)
#define TT 256
#define BB 32
#define EE 512
#define HH 256
#define GG 1024   // 4*H
#define NK 17

typedef __attribute__((ext_vector_type(8))) short bf16x8;
typedef __attribute__((ext_vector_type(4))) float f32x4;

__device__ __forceinline__ int dot4i8(int a, int b, int c) {
#if __has_builtin(__builtin_amdgcn_sdot4)
  return __builtin_amdgcn_sdot4(a, b, c, false);
#else
  int r = c;
#pragma unroll
  for (int e = 0; e < 4; ++e) {
    int av = (a << (24 - 8 * e)) >> 24;
    int bv = (b << (24 - 8 * e)) >> 24;
    r += av * bv;
  }
  return r;
#endif
}

__device__ __forceinline__ short f2bf(float f) {
  unsigned int u = __float_as_uint(f);
  unsigned int rounding = 0x7FFFu + ((u >> 16) & 1u);
  return (short)((u + rounding) >> 16);
}

// ---------------------------------------------------------------- embedding
__global__ void k_embed(const int* __restrict__ src,
                        const float* __restrict__ emb,
                        float* __restrict__ xin) {
  int row = blockIdx.x;                 // b*T + t, 8192 rows
  int v = src[row];                     // emb[0] is all-zero, so padding is fine
  const float4* e = reinterpret_cast<const float4*>(emb + (size_t)v * EE);
  float4* o = reinterpret_cast<float4*>(xin + (size_t)row * EE);
  o[threadIdx.x] = e[threadIdx.x];      // 128 threads * 16B
}

// ---------------------------------------------------------------- f32 -> bf16
__global__ __launch_bounds__(256) void k_cvt(const float* __restrict__ in,
                                             short* __restrict__ out) {
  int i = (blockIdx.x * 256 + threadIdx.x) * 8;
  float4 a = *reinterpret_cast<const float4*>(in + i);
  float4 b = *reinterpret_cast<const float4*>(in + i + 4);
  bf16x8 r;
  r[0] = f2bf(a.x); r[1] = f2bf(a.y); r[2] = f2bf(a.z); r[3] = f2bf(a.w);
  r[4] = f2bf(b.x); r[5] = f2bf(b.y); r[6] = f2bf(b.z); r[7] = f2bf(b.w);
  *reinterpret_cast<bf16x8*>(out + i) = r;
}

// ------------------------------------------------- per-(l,d) max|Whh| (abs bits)
__global__ void k_maxabs(const float* __restrict__ whh, unsigned int* __restrict__ mx) {
  int idx = blockIdx.x * 256 + threadIdx.x;   // < 4*1024*256 = 1048576
  int ld = idx >> 18;                         // block (and wave) spans a single ld
  float v = fabsf(whh[idx]);
#pragma unroll
  for (int off = 32; off > 0; off >>= 1) v = fmaxf(v, __shfl_down(v, off));
  if ((threadIdx.x & 63) == 0) atomicMax(mx + ld, __float_as_uint(v));
}

// ---------------------------------------- Whh -> int8, layout [ld][kk=64][g=1024]
__global__ void k_quant(const float* __restrict__ whh,
                        const unsigned int* __restrict__ mx,
                        int* __restrict__ wq) {
  int idx = blockIdx.x * 256 + threadIdx.x;   // < 4*64*1024 = 262144
  int g = idx & 1023;
  int kk = (idx >> 10) & 63;
  int ld = idx >> 16;
  float inv = 127.f / __uint_as_float(mx[ld]);
  const float* row = whh + ((size_t)(ld * GG + g)) * HH + 4 * kk;
  int q0 = (int)rintf(row[0] * inv);
  int q1 = (int)rintf(row[1] * inv);
  int q2 = (int)rintf(row[2] * inv);
  int q3 = (int)rintf(row[3] * inv);
  wq[idx] = (q0 & 0xFF) | ((q1 & 0xFF) << 8) | ((q2 & 0xFF) << 16) | ((q3 & 0xFF) << 24);
}

__global__ void k_prep_bias(const float* __restrict__ bih,
                            const float* __restrict__ bhh,
                            float* __restrict__ bias) {
  int i = blockIdx.x * 256 + threadIdx.x;     // < 4096
  bias[i] = bih[i] + bhh[i];
}

// ------------------------------------------------------- bf16 MFMA xg GEMM
// out[m][g] = sum_k X[m][k]*W[g][k] + bias[g];  M=8192, N=1024, K=512
// 128x128 tile, 4 waves (2x2), each wave 64x64 = 4x4 frags of 16x16.
__global__ __launch_bounds__(256) void k_gemm_mfma(
    const short* __restrict__ Xb,   // [8192][512] bf16
    const short* __restrict__ Wb,   // [1024][512] bf16 (this (l,d) slice)
    const float* __restrict__ bias, // [1024]
    float* __restrict__ out) {      // [8192][1024] f32
  __shared__ short As[128][40];     // +8 pad: bank stride 20 -> conflict-free-ish
  __shared__ short Bs[128][40];
  const int tid = threadIdx.x;
  const int wave = tid >> 6, lane = tid & 63;
  const int wr = wave >> 1, wc = wave & 1;
  const int m0 = blockIdx.y * 128, n0 = blockIdx.x * 128;
  f32x4 acc[4][4] = {};             // [mi][ni]
  const int cid0 = tid * 2;
  for (int k0 = 0; k0 < EE; k0 += 32) {
#pragma unroll
    for (int u = 0; u < 2; ++u) {
      int cid = cid0 + u;
      int row = cid >> 2, kc = cid & 3;
      *reinterpret_cast<int4*>(&As[row][kc * 8]) =
          *reinterpret_cast<const int4*>(Xb + (size_t)(m0 + row) * EE + k0 + kc * 8);
      *reinterpret_cast<int4*>(&Bs[row][kc * 8]) =
          *reinterpret_cast<const int4*>(Wb + (size_t)(n0 + row) * EE + k0 + kc * 8);
    }
    __syncthreads();
    bf16x8 af[4], bff[4];
#pragma unroll
    for (int mi = 0; mi < 4; ++mi)
      af[mi] = *reinterpret_cast<const bf16x8*>(&As[wr * 64 + mi * 16 + (lane & 15)][(lane >> 4) * 8]);
#pragma unroll
    for (int ni = 0; ni < 4; ++ni)
      bff[ni] = *reinterpret_cast<const bf16x8*>(&Bs[wc * 64 + ni * 16 + (lane & 15)][(lane >> 4) * 8]);
#pragma unroll
    for (int mi = 0; mi < 4; ++mi)
#pragma unroll
      for (int ni = 0; ni < 4; ++ni)
        acc[mi][ni] = __builtin_amdgcn_mfma_f32_16x16x32_bf16(af[mi], bff[ni], acc[mi][ni], 0, 0, 0);
    __syncthreads();
  }
  const int r0 = (lane >> 4) * 4, cc = lane & 15;
#pragma unroll
  for (int mi = 0; mi < 4; ++mi)
#pragma unroll
    for (int ni = 0; ni < 4; ++ni) {
      int g = n0 + wc * 64 + ni * 16 + cc;
      float bv = bias[g];
#pragma unroll
      for (int j = 0; j < 4; ++j) {
        int m = m0 + wr * 64 + mi * 16 + r0 + j;
        out[(size_t)m * GG + g] = acc[mi][ni][j] + bv;
      }
    }
}

// ------------------------------------------------------------- LSTM recurrence
// One block per (b,dir); 512 threads; weights int8 register-resident
// (128 VGPRs/lane, asm-pinned against rematerialization).
__global__ __launch_bounds__(512, 1) void k_rec(
    const float* __restrict__ xg,        // [2][8192][1024] dir-major, bias included
    const int* __restrict__ wq,          // this layer: [2][64][1024] packed int8
    const unsigned int* __restrict__ mx, // this layer: [2] abs-max bits
    const int* __restrict__ lens,        // [32]
    float* __restrict__ outx)            // [8192][512]: [:256]=fwd, [256:]=bwd
{
  const int bid = blockIdx.x;            // 0..63
  const int b = bid & 31;
  const int dir = bid >> 5;
  const int L = threadIdx.x;             // 0..511
  const int g0 = L, g1 = L + 512;        // covers i,f | g,o gate columns
  __shared__ float pre[GG];
  __shared__ __align__(16) int hq[64];   // 256 int8 h values
  const float f = __uint_as_float(mx[dir]) / (127.f * 127.f);
  const int* wp = wq + (size_t)dir * 64 * 1024;
  int w0[64], w1[64];
#pragma unroll
  for (int kk = 0; kk < 64; ++kk) {
    w0[kk] = wp[kk * 1024 + g0];
    w1[kk] = wp[kk * 1024 + g1];
  }
  // pin: values now defined by asm -> compiler cannot rematerialize via reload
#pragma unroll
  for (int kk = 0; kk < 64; ++kk) {
    asm volatile("" : "+v"(w0[kk]));
    asm volatile("" : "+v"(w1[kk]));
  }
  if (L < 64) hq[L] = 0;
  float c = 0.f;
  const int len = lens[b];
  const float* xgb = xg + ((size_t)dir * (BB * TT) + (size_t)b * TT) * GG;
  __syncthreads();
  for (int s = 0; s < TT; ++s) {
    const int t = dir ? (TT - 1 - s) : s;
    float xv0 = xgb[(size_t)t * GG + g0];
    float xv1 = xgb[(size_t)t * GG + g1];
    int a0 = 0, a1 = 0;
    const uint4* h4 = reinterpret_cast<const uint4*>(hq);
#pragma unroll
    for (int q = 0; q < 16; ++q) {
      uint4 hv = h4[q];
      a0 = dot4i8(w0[4 * q + 0], (int)hv.x, a0);
      a0 = dot4i8(w0[4 * q + 1], (int)hv.y, a0);
      a0 = dot4i8(w0[4 * q + 2], (int)hv.z, a0);
      a0 = dot4i8(w0[4 * q + 3], (int)hv.w, a0);
      a1 = dot4i8(w1[4 * q + 0], (int)hv.x, a1);
      a1 = dot4i8(w1[4 * q + 1], (int)hv.y, a1);
      a1 = dot4i8(w1[4 * q + 2], (int)hv.z, a1);
      a1 = dot4i8(w1[4 * q + 3], (int)hv.w, a1);
    }
    pre[g0] = xv0 + (float)a0 * f;
    pre[g1] = xv1 + (float)a1 * f;
    __syncthreads();                     // bar1: pre[] complete (hq reads done too)
    if (L < HH) {
      float gi = pre[L], gf = pre[HH + L], g2 = pre[2 * HH + L], go = pre[3 * HH + L];
      float iv = 1.f / (1.f + expf(-gi));
      float fv = 1.f / (1.f + expf(-gf));
      float gv = tanhf(g2);
      float ov = 1.f / (1.f + expf(-go));
      float cn = fv * c + iv * gv;
      float hn = ov * tanhf(cn);
      const bool m = (t < len);
      outx[((size_t)(b * TT) + t) * (2 * HH) + dir * HH + L] = m ? hn : 0.f;
      if (m) {
        c = cn;
        reinterpret_cast<char*>(hq)[L] = (char)(int)rintf(hn * 127.f);
      }
    }
    __syncthreads();                     // bar2: hq holds h^{s+1}
  }
}

// ------------------------------------------------------------- logits
__global__ __launch_bounds__(256) void k_logits(
    const float* __restrict__ feats,  // [8192][512] f32
    const float* __restrict__ wlin,   // [17][512] f32
    const float* __restrict__ blin,   // [17]
    float* __restrict__ logits) {     // [8192][17]
  int o = blockIdx.x * 256 + threadIdx.x;      // < 8192*17 = 139264 exactly
  int m = o / NK, jj = o - m * NK;
  const float4* fr = reinterpret_cast<const float4*>(feats + (size_t)m * EE);
  const float4* wr = reinterpret_cast<const float4*>(wlin + (size_t)jj * EE);
  float s = blin[jj];
  for (int q = 0; q < EE / 4; ++q) {
    float4 fv = fr[q], wv = wr[q];
    s = fmaf(fv.x, wv.x, s);
    s = fmaf(fv.y, wv.y, s);
    s = fmaf(fv.z, wv.z, s);
    s = fmaf(fv.w, wv.w, s);
  }
  logits[o] = s;
}

// ------------------------------------------------------------- CRF NLL per batch
__global__ __launch_bounds__(64) void k_crf(
    const float* __restrict__ logits,   // [32][256][17]
    const int* __restrict__ labels,     // [32][256]
    const int* __restrict__ lens,       // [32]
    const float* __restrict__ trans,    // [17][17]
    const float* __restrict__ startv,   // [17]
    const float* __restrict__ endv,     // [17]
    float* __restrict__ res) {          // [32] = numerator - partition
  const int b = blockIdx.x;
  const int tid = threadIdx.x;          // one wave
  __shared__ float trs[NK * NK];
  __shared__ float alpha[NK];
  for (int i = tid; i < NK * NK; i += 64) trs[i] = trans[i];
  const int len = lens[b];
  const int* lab = labels + b * TT;
  const float* lg = logits + (size_t)b * TT * NK;
  float part = 0.f;
  for (int t = tid; t < TT; t += 64)
    if (t < len) part += lg[t * NK + lab[t]];
  __syncthreads();
  for (int t = tid; t < TT - 1; t += 64)
    if (t + 1 < len) part += trs[lab[t] * NK + lab[t + 1]];
#pragma unroll
  for (int off = 32; off > 0; off >>= 1) part += __shfl_down(part, off);
  if (tid < NK) alpha[tid] = startv[tid] + lg[tid];
  __syncthreads();
  const int tmax = (len < TT) ? len : TT;
  for (int t = 1; t < tmax; ++t) {
    float nv = 0.f;
    if (tid < NK) {
      float mxv = -1e30f;
#pragma unroll
      for (int i = 0; i < NK; ++i) mxv = fmaxf(mxv, alpha[i] + trs[i * NK + tid]);
      float sum = 0.f;
#pragma unroll
      for (int i = 0; i < NK; ++i) sum += expf(alpha[i] + trs[i * NK + tid] - mxv);
      nv = mxv + logf(sum) + lg[t * NK + tid];
    }
    __syncthreads();
    if (tid < NK) alpha[tid] = nv;
    __syncthreads();
  }
  if (tid == 0) {
    float mxv = -1e30f;
    float av[NK];
    for (int i = 0; i < NK; ++i) { av[i] = alpha[i] + endv[i]; mxv = fmaxf(mxv, av[i]); }
    float sum = 0.f;
    for (int i = 0; i < NK; ++i) sum += expf(av[i] - mxv);
    float partition = mxv + logf(sum);
    float numer = startv[lab[0]] + part + endv[lab[len - 1]];
    res[b] = numer - partition;
  }
}

__global__ void k_final(const float* __restrict__ res, float* __restrict__ out) {
  int tid = threadIdx.x;  // 64
  float v = (tid < BB) ? res[tid] : 0.f;
#pragma unroll
  for (int off = 32; off > 0; off >>= 1) v += __shfl_down(v, off);
  if (tid == 0) out[0] = -v;
}

extern "C" void kernel_launch(void* const* d_in, const int* in_sizes, int n_in,
                              void* d_out, int out_size, void* d_ws, size_t ws_size,
                              hipStream_t stream) {
  const int* src = (const int*)d_in[0];
  const int* lens = (const int*)d_in[1];
  const int* labels = (const int*)d_in[2];
  // d_in[3] = decode (always 0, ignored)
  const float* emb = (const float*)d_in[4];
  const float* Wih = (const float*)d_in[5];
  const float* Whh = (const float*)d_in[6];
  const float* bih = (const float*)d_in[7];
  const float* bhh = (const float*)d_in[8];
  const float* Wlin = (const float*)d_in[9];
  const float* blin = (const float*)d_in[10];
  const float* trans = (const float*)d_in[11];
  const float* startv = (const float*)d_in[12];
  const float* endv = (const float*)d_in[13];

  char* w = (char*)d_ws;
  float* xin0 = (float*)w;  w += (size_t)BB * TT * EE * 4;        // 16.8 MB
  float* xin1 = (float*)w;  w += (size_t)BB * TT * EE * 4;        // 16.8 MB
  float* xg = (float*)w;    w += (size_t)2 * BB * TT * GG * 4;    // 67.1 MB
  int* wq = (int*)w;        w += (size_t)4 * 64 * 1024 * 4;       // 1.05 MB
  unsigned int* mxb = (unsigned int*)w; w += 256;                 // 4 maxabs
  float* biasb = (float*)w; w += (size_t)2 * 2 * GG * 4;          // 16 KB
  float* logits = (float*)w; w += (size_t)BB * TT * NK * 4;       // 557 KB
  float* res = (float*)w;   w += 256;
  short* xb = (short*)w;    w += (size_t)BB * TT * EE * 2;        // 8.4 MB
  short* wbb = (short*)w;   w += (size_t)4 * GG * EE * 2;         // 4.2 MB

  hipMemsetAsync(mxb, 0, 16, stream);
  k_embed<<<BB * TT, 128, 0, stream>>>(src, emb, xin0);
  k_maxabs<<<4096, 256, 0, stream>>>(Whh, mxb);
  k_quant<<<1024, 256, 0, stream>>>(Whh, mxb, wq);
  k_prep_bias<<<16, 256, 0, stream>>>(bih, bhh, biasb);
  k_cvt<<<(4 * GG * EE) / (256 * 8), 256, 0, stream>>>(Wih, wbb);

  for (int l = 0; l < 2; ++l) {
    const float* xin = l ? xin1 : xin0;
    float* xout = l ? xin0 : xin1;
    k_cvt<<<(BB * TT * EE) / (256 * 8), 256, 0, stream>>>(xin, xb);
    for (int d = 0; d < 2; ++d) {
      k_gemm_mfma<<<dim3(GG / 128, (BB * TT) / 128), 256, 0, stream>>>(
          xb, wbb + ((size_t)(l * 2 + d)) * GG * EE,
          biasb + (l * 2 + d) * GG, xg + (size_t)d * BB * TT * GG);
    }
    k_rec<<<64, 512, 0, stream>>>(xg, wq + (size_t)l * 2 * 64 * 1024, mxb + l * 2,
                                  lens, xout);
  }

  k_logits<<<(BB * TT * NK) / 256, 256, 0, stream>>>(xin0, Wlin, blin, logits);
  k_crf<<<BB, 64, 0, stream>>>(logits, labels, lens, trans, startv, endv, res);
  k_final<<<1, 64, 0, stream>>>(res, (float*)d_out);
}

// Round 6
// 1115.974 us; speedup vs baseline: 4.6406x; 1.0144x over previous
//
#include <hip/hip_runtime.h>

// Sizes (fixed by the problem)
#define TT 256
#define BB 32
#define EE 512
#define HH 256
#define GG 1024   // 4*H
#define NK 17

typedef __attribute__((ext_vector_type(8))) short bf16x8;
typedef __attribute__((ext_vector_type(4))) float f32x4;

__device__ __forceinline__ int dot4i8(int a, int b, int c) {
#if __has_builtin(__builtin_amdgcn_sdot4)
  return __builtin_amdgcn_sdot4(a, b, c, false);
#else
  int r = c;
#pragma unroll
  for (int e = 0; e < 4; ++e) {
    int av = (a << (24 - 8 * e)) >> 24;
    int bv = (b << (24 - 8 * e)) >> 24;
    r += av * bv;
  }
  return r;
#endif
}

__device__ __forceinline__ short f2bf(float f) {
  unsigned int u = __float_as_uint(f);
  unsigned int rounding = 0x7FFFu + ((u >> 16) & 1u);
  return (short)((u + rounding) >> 16);
}
__device__ __forceinline__ float bfu2f_lo(unsigned int u) {  // low bf16 of dword
  return __uint_as_float(u << 16);
}
__device__ __forceinline__ float bfu2f_hi(unsigned int u) {  // high bf16 of dword
  return __uint_as_float(u & 0xFFFF0000u);
}

// ------------------------------------------------- embedding -> bf16 features
__global__ void k_embed(const int* __restrict__ src,
                        const float* __restrict__ emb,
                        short* __restrict__ xb) {
  int row = blockIdx.x;                 // b*T + t, 8192 rows
  int v = src[row];                     // emb[0] is all-zero, so padding is fine
  int t = threadIdx.x;                  // 64 threads, 8 elems each
  const float4* e = reinterpret_cast<const float4*>(emb + (size_t)v * EE) + 2 * t;
  float4 a = e[0], b = e[1];
  bf16x8 r;
  r[0] = f2bf(a.x); r[1] = f2bf(a.y); r[2] = f2bf(a.z); r[3] = f2bf(a.w);
  r[4] = f2bf(b.x); r[5] = f2bf(b.y); r[6] = f2bf(b.z); r[7] = f2bf(b.w);
  *reinterpret_cast<bf16x8*>(xb + (size_t)row * EE + 8 * t) = r;
}

// ---------------------------------------------------------------- f32 -> bf16
__global__ __launch_bounds__(256) void k_cvt(const float* __restrict__ in,
                                             short* __restrict__ out) {
  int i = (blockIdx.x * 256 + threadIdx.x) * 8;
  float4 a = *reinterpret_cast<const float4*>(in + i);
  float4 b = *reinterpret_cast<const float4*>(in + i + 4);
  bf16x8 r;
  r[0] = f2bf(a.x); r[1] = f2bf(a.y); r[2] = f2bf(a.z); r[3] = f2bf(a.w);
  r[4] = f2bf(b.x); r[5] = f2bf(b.y); r[6] = f2bf(b.z); r[7] = f2bf(b.w);
  *reinterpret_cast<bf16x8*>(out + i) = r;
}

// ------------------------------------------------- per-(l,d) max|Whh| (abs bits)
__global__ void k_maxabs(const float* __restrict__ whh, unsigned int* __restrict__ mx) {
  int idx = blockIdx.x * 256 + threadIdx.x;   // < 4*1024*256 = 1048576
  int ld = idx >> 18;                         // block (and wave) spans a single ld
  float v = fabsf(whh[idx]);
#pragma unroll
  for (int off = 32; off > 0; off >>= 1) v = fmaxf(v, __shfl_down(v, off));
  if ((threadIdx.x & 63) == 0) atomicMax(mx + ld, __float_as_uint(v));
}

// ---------------------------------------- Whh -> int8, layout [ld][kk=64][g=1024]
__global__ void k_quant(const float* __restrict__ whh,
                        const unsigned int* __restrict__ mx,
                        int* __restrict__ wq) {
  int idx = blockIdx.x * 256 + threadIdx.x;   // < 4*64*1024 = 262144
  int g = idx & 1023;
  int kk = (idx >> 10) & 63;
  int ld = idx >> 16;
  float inv = 127.f / __uint_as_float(mx[ld]);
  const float* row = whh + ((size_t)(ld * GG + g)) * HH + 4 * kk;
  int q0 = (int)rintf(row[0] * inv);
  int q1 = (int)rintf(row[1] * inv);
  int q2 = (int)rintf(row[2] * inv);
  int q3 = (int)rintf(row[3] * inv);
  wq[idx] = (q0 & 0xFF) | ((q1 & 0xFF) << 8) | ((q2 & 0xFF) << 16) | ((q3 & 0xFF) << 24);
}

__global__ void k_prep_bias(const float* __restrict__ bih,
                            const float* __restrict__ bhh,
                            float* __restrict__ bias) {
  int i = blockIdx.x * 256 + threadIdx.x;     // < 4096
  bias[i] = bih[i] + bhh[i];
}

// ------------------------------------------------- bf16 MFMA xg GEMM (merged dirs)
// For one layer: out[d][m][g] = sum_k X[m][k]*W[d*1024+g][k] + bias[d*1024+g]
// M=8192, N=2048, K=512. 128x128 tile, 4 waves (2x2), wave 64x64 = 4x4 frags.
__global__ __launch_bounds__(256) void k_gemm_mfma(
    const short* __restrict__ Xb,   // [8192][512] bf16
    const short* __restrict__ Wb,   // [2048][512] bf16 (this layer, both dirs)
    const float* __restrict__ bias, // [2048]
    float* __restrict__ out) {      // [2][8192][1024] f32
  __shared__ short As[128][40];     // +8 pad
  __shared__ short Bs[128][40];
  const int tid = threadIdx.x;
  const int wave = tid >> 6, lane = tid & 63;
  const int wr = wave >> 1, wc = wave & 1;
  const int m0 = blockIdx.y * 128, n0 = blockIdx.x * 128;
  f32x4 acc[4][4] = {};             // [mi][ni]
  const int cid0 = tid * 2;
  for (int k0 = 0; k0 < EE; k0 += 32) {
#pragma unroll
    for (int u = 0; u < 2; ++u) {
      int cid = cid0 + u;
      int row = cid >> 2, kc = cid & 3;
      *reinterpret_cast<int4*>(&As[row][kc * 8]) =
          *reinterpret_cast<const int4*>(Xb + (size_t)(m0 + row) * EE + k0 + kc * 8);
      *reinterpret_cast<int4*>(&Bs[row][kc * 8]) =
          *reinterpret_cast<const int4*>(Wb + (size_t)(n0 + row) * EE + k0 + kc * 8);
    }
    __syncthreads();
    bf16x8 af[4], bff[4];
#pragma unroll
    for (int mi = 0; mi < 4; ++mi)
      af[mi] = *reinterpret_cast<const bf16x8*>(&As[wr * 64 + mi * 16 + (lane & 15)][(lane >> 4) * 8]);
#pragma unroll
    for (int ni = 0; ni < 4; ++ni)
      bff[ni] = *reinterpret_cast<const bf16x8*>(&Bs[wc * 64 + ni * 16 + (lane & 15)][(lane >> 4) * 8]);
#pragma unroll
    for (int mi = 0; mi < 4; ++mi)
#pragma unroll
      for (int ni = 0; ni < 4; ++ni)
        acc[mi][ni] = __builtin_amdgcn_mfma_f32_16x16x32_bf16(af[mi], bff[ni], acc[mi][ni], 0, 0, 0);
    __syncthreads();
  }
  const int r0 = (lane >> 4) * 4, cc = lane & 15;
#pragma unroll
  for (int mi = 0; mi < 4; ++mi)
#pragma unroll
    for (int ni = 0; ni < 4; ++ni) {
      int gcol = n0 + wc * 64 + ni * 16 + cc;      // 0..2047
      int dir = gcol >> 10, gg = gcol & 1023;
      float bv = bias[gcol];
      float* ob = out + (size_t)dir * (BB * TT * GG) + gg;
#pragma unroll
      for (int j = 0; j < 4; ++j) {
        int m = m0 + wr * 64 + mi * 16 + r0 + j;
        ob[(size_t)m * GG] = acc[mi][ni][j] + bv;
      }
    }
}

// ------------------------------------------------------------- LSTM recurrence
// One block per (b,dir); 1024 threads; each lane owns ONE gate column with all
// 256 K weights in 64 NAMED int registers (no arrays -> no scratch demotion).
#define R16(M) M(0) M(1) M(2) M(3) M(4) M(5) M(6) M(7) \
               M(8) M(9) M(10) M(11) M(12) M(13) M(14) M(15)
#define DECLW(i) int wa##i, wb##i, wc##i, wd##i;
#define LOADW(i) wa##i = wp[(4 * i + 0) * 1024]; \
                 wb##i = wp[(4 * i + 1) * 1024]; \
                 wc##i = wp[(4 * i + 2) * 1024]; \
                 wd##i = wp[(4 * i + 3) * 1024];
#define PINW(i) asm volatile("" : "+v"(wa##i), "+v"(wb##i), "+v"(wc##i), "+v"(wd##i));
#define DOTW(i) { uint4 hv = h4[i]; \
                  acc = dot4i8(wa##i, (int)hv.x, acc); \
                  acc = dot4i8(wb##i, (int)hv.y, acc); \
                  acc = dot4i8(wc##i, (int)hv.z, acc); \
                  acc = dot4i8(wd##i, (int)hv.w, acc); }

__global__ __launch_bounds__(1024, 4) void k_rec(
    const float* __restrict__ xg,        // [2][8192][1024] dir-major, bias included
    const int* __restrict__ wq,          // this layer: [2][64][1024] packed int8
    const unsigned int* __restrict__ mx, // this layer: [2] abs-max bits
    const int* __restrict__ lens,        // [32]
    short* __restrict__ outx)            // [8192][512] bf16: [:256]=fwd, [256:]=bwd
{
  const int bid = blockIdx.x;            // 0..63
  const int b = bid & 31;
  const int dir = bid >> 5;
  const int g = threadIdx.x;             // 0..1023 = gate column
  __shared__ float pre[GG];
  __shared__ __align__(16) int hq[64];   // 256 int8 h values
  const float f = __uint_as_float(mx[dir]) / (127.f * 127.f);
  const int* wp = wq + (size_t)dir * 64 * 1024 + g;
  DECLW(0) DECLW(1) DECLW(2) DECLW(3) DECLW(4) DECLW(5) DECLW(6) DECLW(7)
  DECLW(8) DECLW(9) DECLW(10) DECLW(11) DECLW(12) DECLW(13) DECLW(14) DECLW(15)
  R16(LOADW)
  R16(PINW)
  if (g < 64) hq[g] = 0;
  float c = 0.f;
  const int len = lens[b];
  const float* xgb = xg + ((size_t)dir * (BB * TT) + (size_t)b * TT) * GG + g;
  __syncthreads();
  for (int s = 0; s < TT; ++s) {
    const int t = dir ? (TT - 1 - s) : s;
    float xv = xgb[(size_t)t * GG];
    int acc = 0;
    const uint4* h4 = reinterpret_cast<const uint4*>(hq);
    R16(DOTW)
    pre[g] = xv + (float)acc * f;
    __syncthreads();                     // bar1: pre[] complete, hq reads done
    if (g < HH) {
      float gi = pre[g], gf = pre[HH + g], g2 = pre[2 * HH + g], go = pre[3 * HH + g];
      float iv = 1.f / (1.f + expf(-gi));
      float fv = 1.f / (1.f + expf(-gf));
      float gv = tanhf(g2);
      float ov = 1.f / (1.f + expf(-go));
      float cn = fv * c + iv * gv;
      float hn = ov * tanhf(cn);
      const bool m = (t < len);
      outx[((size_t)(b * TT) + t) * (2 * HH) + dir * HH + g] = f2bf(m ? hn : 0.f);
      if (m) {
        c = cn;
        reinterpret_cast<char*>(hq)[g] = (char)(int)rintf(hn * 127.f);
      }
    }
    __syncthreads();                     // bar2: hq holds h^{s+1}
  }
}

// ------------------------------------------------------------- logits (bf16 feats)
__global__ __launch_bounds__(256) void k_logits(
    const short* __restrict__ feats,  // [8192][512] bf16
    const float* __restrict__ wlin,   // [17][512] f32
    const float* __restrict__ blin,   // [17]
    float* __restrict__ logits) {     // [8192][17]
  int o = blockIdx.x * 256 + threadIdx.x;      // < 8192*17 = 139264 exactly
  int m = o / NK, jj = o - m * NK;
  const uint4* fr = reinterpret_cast<const uint4*>(feats + (size_t)m * EE);
  const float4* wr = reinterpret_cast<const float4*>(wlin + (size_t)jj * EE);
  float s = blin[jj];
  for (int q = 0; q < EE / 8; ++q) {
    uint4 fv = fr[q];
    float4 w0 = wr[2 * q], w1 = wr[2 * q + 1];
    s = fmaf(bfu2f_lo(fv.x), w0.x, s);
    s = fmaf(bfu2f_hi(fv.x), w0.y, s);
    s = fmaf(bfu2f_lo(fv.y), w0.z, s);
    s = fmaf(bfu2f_hi(fv.y), w0.w, s);
    s = fmaf(bfu2f_lo(fv.z), w1.x, s);
    s = fmaf(bfu2f_hi(fv.z), w1.y, s);
    s = fmaf(bfu2f_lo(fv.w), w1.z, s);
    s = fmaf(bfu2f_hi(fv.w), w1.w, s);
  }
  logits[o] = s;
}

// ------------------------------------------------------------- CRF NLL per batch
__global__ __launch_bounds__(64) void k_crf(
    const float* __restrict__ logits,   // [32][256][17]
    const int* __restrict__ labels,     // [32][256]
    const int* __restrict__ lens,       // [32]
    const float* __restrict__ trans,    // [17][17]
    const float* __restrict__ startv,   // [17]
    const float* __restrict__ endv,     // [17]
    float* __restrict__ res) {          // [32] = numerator - partition
  const int b = blockIdx.x;
  const int tid = threadIdx.x;          // one wave
  __shared__ float trs[NK * NK];
  __shared__ float alpha[NK];
  for (int i = tid; i < NK * NK; i += 64) trs[i] = trans[i];
  const int len = lens[b];
  const int* lab = labels + b * TT;
  const float* lg = logits + (size_t)b * TT * NK;
  float part = 0.f;
  for (int t = tid; t < TT; t += 64)
    if (t < len) part += lg[t * NK + lab[t]];
  __syncthreads();
  for (int t = tid; t < TT - 1; t += 64)
    if (t + 1 < len) part += trs[lab[t] * NK + lab[t + 1]];
#pragma unroll
  for (int off = 32; off > 0; off >>= 1) part += __shfl_down(part, off);
  if (tid < NK) alpha[tid] = startv[tid] + lg[tid];
  __syncthreads();
  const int tmax = (len < TT) ? len : TT;
  for (int t = 1; t < tmax; ++t) {
    float nv = 0.f;
    if (tid < NK) {
      float mxv = -1e30f;
#pragma unroll
      for (int i = 0; i < NK; ++i) mxv = fmaxf(mxv, alpha[i] + trs[i * NK + tid]);
      float sum = 0.f;
#pragma unroll
      for (int i = 0; i < NK; ++i) sum += expf(alpha[i] + trs[i * NK + tid] - mxv);
      nv = mxv + logf(sum) + lg[t * NK + tid];
    }
    __syncthreads();
    if (tid < NK) alpha[tid] = nv;
    __syncthreads();
  }
  if (tid == 0) {
    float mxv = -1e30f;
    float av[NK];
    for (int i = 0; i < NK; ++i) { av[i] = alpha[i] + endv[i]; mxv = fmaxf(mxv, av[i]); }
    float sum = 0.f;
    for (int i = 0; i < NK; ++i) sum += expf(av[i] - mxv);
    float partition = mxv + logf(sum);
    float numer = startv[lab[0]] + part + endv[lab[len - 1]];
    res[b] = numer - partition;
  }
}

__global__ void k_final(const float* __restrict__ res, float* __restrict__ out) {
  int tid = threadIdx.x;  // 64
  float v = (tid < BB) ? res[tid] : 0.f;
#pragma unroll
  for (int off = 32; off > 0; off >>= 1) v += __shfl_down(v, off);
  if (tid == 0) out[0] = -v;
}

extern "C" void kernel_launch(void* const* d_in, const int* in_sizes, int n_in,
                              void* d_out, int out_size, void* d_ws, size_t ws_size,
                              hipStream_t stream) {
  const int* src = (const int*)d_in[0];
  const int* lens = (const int*)d_in[1];
  const int* labels = (const int*)d_in[2];
  // d_in[3] = decode (always 0, ignored)
  const float* emb = (const float*)d_in[4];
  const float* Wih = (const float*)d_in[5];
  const float* Whh = (const float*)d_in[6];
  const float* bih = (const float*)d_in[7];
  const float* bhh = (const float*)d_in[8];
  const float* Wlin = (const float*)d_in[9];
  const float* blin = (const float*)d_in[10];
  const float* trans = (const float*)d_in[11];
  const float* startv = (const float*)d_in[12];
  const float* endv = (const float*)d_in[13];

  char* w = (char*)d_ws;
  short* xb0 = (short*)w;   w += (size_t)BB * TT * EE * 2;        // 8.4 MB
  short* xb1 = (short*)w;   w += (size_t)BB * TT * EE * 2;        // 8.4 MB
  short* xb2 = (short*)w;   w += (size_t)BB * TT * EE * 2;        // 8.4 MB
  float* xg = (float*)w;    w += (size_t)2 * BB * TT * GG * 4;    // 67.1 MB
  int* wq = (int*)w;        w += (size_t)4 * 64 * 1024 * 4;       // 1.05 MB
  unsigned int* mxb = (unsigned int*)w; w += 256;                 // 4 maxabs
  float* biasb = (float*)w; w += (size_t)2 * 2 * GG * 4;          // 16 KB
  float* logits = (float*)w; w += (size_t)BB * TT * NK * 4;       // 557 KB
  float* res = (float*)w;   w += 256;
  short* wbb = (short*)w;   w += (size_t)4 * GG * EE * 2;         // 4.2 MB

  hipMemsetAsync(mxb, 0, 16, stream);
  k_embed<<<BB * TT, 64, 0, stream>>>(src, emb, xb0);
  k_maxabs<<<4096, 256, 0, stream>>>(Whh, mxb);
  k_quant<<<1024, 256, 0, stream>>>(Whh, mxb, wq);
  k_prep_bias<<<16, 256, 0, stream>>>(bih, bhh, biasb);
  k_cvt<<<(4 * GG * EE) / (256 * 8), 256, 0, stream>>>(Wih, wbb);

  const short* xin[2] = {xb0, xb1};
  short* xout[2] = {xb1, xb2};
  for (int l = 0; l < 2; ++l) {
    k_gemm_mfma<<<dim3(2 * GG / 128, (BB * TT) / 128), 256, 0, stream>>>(
        xin[l], wbb + (size_t)l * 2 * GG * EE, biasb + l * 2 * GG, xg);
    k_rec<<<64, 1024, 0, stream>>>(xg, wq + (size_t)l * 2 * 64 * 1024, mxb + l * 2,
                                   lens, xout[l]);
  }

  k_logits<<<(BB * TT * NK) / 256, 256, 0, stream>>>(xb2, Wlin, blin, logits);
  k_crf<<<BB, 64, 0, stream>>>(logits, labels, lens, trans, startv, endv, res);
  k_final<<<1, 64, 0, stream>>>(res, (float*)d_out);
}